// Round 15
// baseline (388.631 us; speedup 1.0000x reference)
//
#include <hip/hip_runtime.h>
#include <hip/hip_bf16.h>
#include <math.h>

typedef unsigned short u16;
typedef __attribute__((ext_vector_type(8))) short short8;
typedef __attribute__((ext_vector_type(4))) float f32x4;

#define B_ 2
#define S_ 1025
#define D_ 1024
#define H_ 16
#define HD_ 64
#define P_ 1024
#define K_ 32
#define NS_ 16   // attn_cls S-splits

static constexpr float TEMP_ = 0.1f;
static constexpr float SCALE_ = 0.125f;
static constexpr float EPS_LN_ = 1e-5f;

__device__ __forceinline__ float bf2f(u16 u) {
  unsigned int t = ((unsigned int)u) << 16;
  float f;
  __builtin_memcpy(&f, &t, 4);
  return f;
}
__device__ __forceinline__ u16 f2bf(float f) {
  __hip_bfloat16 h = __float2bfloat16(f);
  u16 u;
  __builtin_memcpy(&u, &h, 2);
  return u;
}
__device__ __forceinline__ float gelu_f(float x) {
  return 0.5f * x * (1.0f + erff(x * 0.70710678118654752f));
}

typedef __attribute__((address_space(1))) const unsigned int gas_u32;
typedef __attribute__((address_space(3))) unsigned int las_u32;
__device__ __forceinline__ void g2l16(const void* g, void* l) {
  __builtin_amdgcn_global_load_lds((gas_u32*)g, (las_u32*)l, 16, 0, 0);
}

// ---- fused flat f32->bf16 convert of up to 4 contiguous tensors ----
__global__ __launch_bounds__(256) void conv4_kernel(
    const float* __restrict__ s0, int n0, const float* __restrict__ s1, int n1,
    const float* __restrict__ s2, int n2, const float* __restrict__ s3, int n3,
    u16* __restrict__ dst) {
  const int e = (blockIdx.x * 256 + threadIdx.x) * 4;
  const float* src;
  int off;
  if (e < n0) { src = s0; off = e; }
  else if (e < n0 + n1) { src = s1; off = e - n0; }
  else if (e < n0 + n1 + n2) { src = s2; off = e - n0 - n1; }
  else if (e < n0 + n1 + n2 + n3) { src = s3; off = e - n0 - n1 - n2; }
  else return;
  float4 t = *reinterpret_cast<const float4*>(src + off);
  ushort4 o;
  o.x = f2bf(t.x); o.y = f2bf(t.y); o.z = f2bf(t.z); o.w = f2bf(t.w);
  *reinterpret_cast<ushort4*>(dst + e) = o;
}

// ---- block reductions (256 threads) ----
__device__ __forceinline__ float block_sum256(float v, float* red4) {
  for (int off = 32; off > 0; off >>= 1) v += __shfl_down(v, off);
  if ((threadIdx.x & 63) == 0) red4[threadIdx.x >> 6] = v;
  __syncthreads();
  float r = red4[0] + red4[1] + red4[2] + red4[3];
  __syncthreads();
  return r;
}
__device__ __forceinline__ float block_max256(float v, float* red4) {
  for (int off = 32; off > 0; off >>= 1) v = fmaxf(v, __shfl_down(v, off));
  if ((threadIdx.x & 63) == 0) red4[threadIdx.x >> 6] = v;
  __syncthreads();
  float r = fmaxf(fmaxf(red4[0], red4[1]), fmaxf(red4[2], red4[3]));
  __syncthreads();
  return r;
}

// ---- LayerNorm f32 in -> bf16 out ----
__global__ __launch_bounds__(256) void ln_kernel(const float* __restrict__ x,
                                                 const float* __restrict__ w,
                                                 const float* __restrict__ b,
                                                 u16* __restrict__ out) {
  __shared__ float red4[4];
  const long long base = (long long)blockIdx.x * D_;
  float v[4];
  float s = 0.f, ss = 0.f;
#pragma unroll
  for (int u = 0; u < 4; ++u) {
    int d = threadIdx.x + u * 256;
    float f = x[base + d];
    v[u] = f; s += f; ss += f * f;
  }
  float tot = block_sum256(s, red4);
  float tot2 = block_sum256(ss, red4);
  float mean = tot * (1.0f / D_);
  float var = tot2 * (1.0f / D_) - mean * mean;
  float rstd = rsqrtf(var + EPS_LN_);
#pragma unroll
  for (int u = 0; u < 4; ++u) {
    int d = threadIdx.x + u * 256;
    out[base + d] = f2bf((v[u] - mean) * rstd * w[d] + b[d]);
  }
}

// ---- fused residual + LN2: x1 = x + proj_b + p0 + p1; xnorm = LN(x1) ----
__global__ __launch_bounds__(256) void ln2res_kernel(
    const float* __restrict__ x, const float* __restrict__ pb,
    const float* __restrict__ p0, const float* __restrict__ p1,
    const float* __restrict__ w, const float* __restrict__ b,
    float* __restrict__ x1, u16* __restrict__ out) {
  __shared__ float red4[4];
  const long long base = (long long)blockIdx.x * D_;
  float v[4];
  float s = 0.f, ss = 0.f;
#pragma unroll
  for (int u = 0; u < 4; ++u) {
    int d = threadIdx.x + u * 256;
    float f = x[base + d] + pb[d] + p0[base + d] + p1[base + d];
    x1[base + d] = f;
    v[u] = f; s += f; ss += f * f;
  }
  float tot = block_sum256(s, red4);
  float tot2 = block_sum256(ss, red4);
  float mean = tot * (1.0f / D_);
  float var = tot2 * (1.0f / D_) - mean * mean;
  float rstd = rsqrtf(var + EPS_LN_);
#pragma unroll
  for (int u = 0; u < 4; ++u) {
    int d = threadIdx.x + u * 256;
    out[base + d] = f2bf((v[u] - mean) * rstd * w[d] + b[d]);
  }
}

// ---- final fused reduce: out = x1 + fc2_b + p0 + p1 ----
__global__ __launch_bounds__(256) void fc2red_kernel(
    const float* __restrict__ x1, const float* __restrict__ b,
    const float* __restrict__ p0, const float* __restrict__ p1,
    float* __restrict__ out) {
  const long long base = (long long)blockIdx.x * D_;
#pragma unroll
  for (int u = 0; u < 4; ++u) {
    int d = threadIdx.x + u * 256;
    out[base + d] = x1[base + d] + b[d] + p0[base + d] + p1[base + d];
  }
}

// ---- L2 normalize qr then kr rows in one launch (4096 blocks) ----
__global__ __launch_bounds__(256) void l2norm2_kernel(u16* __restrict__ qr,
                                                      u16* __restrict__ kr) {
  __shared__ float red4[4];
  const int row = blockIdx.x;
  u16* x = (row < 2048) ? qr + (long long)row * D_
                        : kr + (long long)(row - 2048) * D_;
  float v[4];
  float ss = 0.f;
#pragma unroll
  for (int u = 0; u < 4; ++u) {
    int d = threadIdx.x + u * 256;
    v[u] = bf2f(x[d]);
    ss += v[u] * v[u];
  }
  float tot = block_sum256(ss, red4);
  float inv = 1.0f / fmaxf(sqrtf(tot), 1e-12f);
#pragma unroll
  for (int u = 0; u < 4; ++u) {
    int d = threadIdx.x + u * 256;
    x[d] = f2bf(v[u] * inv);
  }
}

// ---- MFMA GEMM body: out[n,m] = sum_k A[n,k]*W[m,k], 64x128 tile, BK=64 ----
// Ledger: r3 2-barrier counted-vmcnt dbuf REGRESSED; r7 deeper split-K
// REGRESSED (atomic tax); r8 XCD swizzle kept (FETCH -76%); r10 64x128 tile
// (TLP null but kept: same perf, less LDS); r13 atomic-free split-K WIN
// (404->383.5, MODE 6 partial slices + fused consumers).
// This round: T3-min 2-phase LDS double-buffer (catalog m248v2 recipe --
// STRUCTURALLY different from r3: issue next-tile STAGE FIRST, compute
// current, then ONE __syncthreads per iter whose implicit vmcnt(0) drains
// the prefetch). Next-tile HBM/L2 latency hides under current-tile
// ds_read+MFMA; one barrier REMOVED vs the naive loop. LDS 48 KiB -> 3
// blocks/CU = current effective residency (r13 occ 34%), so no occupancy
// loss. K-order unchanged -> identical numerics.
// Staging: A 2 chunks + W 4 chunks of (32 rows x 64 k); k granules (16B)
// XOR-swizzled by (row&7) on the GLOBAL src addr -> ds_read conflict-free
// (r2/r8/r10/r13 verified: SQ_LDS_BANK_CONFLICT = 0).
// MODE 0: RQK : m<1024 -> outU=bf16(v+bias[m]); else outU2=bf16(v+bias2[m-1024])
// MODE 2: BIAS: outU = bf16(v + bias[bias_off+m])
// MODE 3: GELU: outU = bf16(gelu(v + bias[bias_off+m]))
// MODE 6: PART: outF[bz*bias_off + n*M + m] = v  (bias_off = slice stride, floats)
template <int MODE>
__device__ __forceinline__ void gemm_body(
    u16* sA, u16* sW,
    const u16* __restrict__ A, long long a_off, const u16* __restrict__ W,
    int N, int M, int Kd, int klen, int rpb, long long a_bs, long long w_bs,
    const float* __restrict__ bias, const float* __restrict__ bias2, int bias_off,
    u16* __restrict__ outU, u16* __restrict__ outU2, float* __restrict__ outF,
    int bx, int by, int bz) {
  const int tid = threadIdx.x;
  const int lane = tid & 63;
  const int q4 = lane >> 4;
  const int r16 = lane & 15;
  const int wave = tid >> 6;
  const int wr = (wave & 1) * 32;   // wave row-group: 2 x 32 rows
  const int wc = (wave >> 1) * 64;  // wave col-group: 2 x 64 cols
  const int row0 = by * 64;
  const int col0 = bx * 128;
  const int batch = row0 / rpb;
  const u16* Ab = A + a_off + (long long)batch * a_bs +
                  (long long)(row0 - batch * rpb) * Kd;
  const u16* Wb = W + (long long)batch * w_bs + (long long)col0 * Kd;
  const int rmax = N - 1 - row0;
  // staging: chunks of (32 rows x 64 k); lds dest = c*2048 + tid*8 (u16)
  const int srow = tid >> 3;                     // row within chunk (0..31)
  const int kx = ((tid & 7) ^ (srow & 7)) * 8;   // swizzled global k-granule
  const int kbeg = bz * klen;
  const int niter = klen >> 6;
  f32x4 acc[2][4] = {};
  // prologue: stage tile 0 into buffer 0; __syncthreads drains (vmcnt 0)
  {
    const int k0 = kbeg;
#pragma unroll
    for (int c = 0; c < 2; ++c) {
      const int rg = c * 32 + srow;
      g2l16(Ab + (long long)min(rg, rmax) * Kd + kx + k0, &sA[c * 2048 + tid * 8]);
    }
#pragma unroll
    for (int c = 0; c < 4; ++c) {
      const int rg = c * 32 + srow;
      g2l16(Wb + (long long)rg * Kd + kx + k0, &sW[c * 2048 + tid * 8]);
    }
  }
  __syncthreads();
  int cur = 0;
  for (int it = 0; it < niter; ++it) {
    // 1. issue next-tile prefetch into buf^1 (latency hides under compute)
    if (it + 1 < niter) {
      const int k0 = kbeg + (it + 1) * 64;
      const int na = (cur ^ 1) * 4096;
      const int nw = (cur ^ 1) * 8192;
#pragma unroll
      for (int c = 0; c < 2; ++c) {
        const int rg = c * 32 + srow;
        g2l16(Ab + (long long)min(rg, rmax) * Kd + kx + k0,
              &sA[na + c * 2048 + tid * 8]);
      }
#pragma unroll
      for (int c = 0; c < 4; ++c) {
        const int rg = c * 32 + srow;
        g2l16(Wb + (long long)rg * Kd + kx + k0, &sW[nw + c * 2048 + tid * 8]);
      }
    }
    // 2. compute current buffer (compiler inserts lgkmcnt for ds_read->MFMA)
    const int ca = cur * 4096;
    const int cw = cur * 8192;
#pragma unroll
    for (int s = 0; s < 2; ++s) {
      short8 a[2], b[4];
      const int ks = ((s * 4 + q4) ^ (r16 & 7)) * 8;
#pragma unroll
      for (int i = 0; i < 2; ++i)
        a[i] = *reinterpret_cast<const short8*>(
            &sA[ca + (wr + i * 16 + r16) * 64 + ks]);
#pragma unroll
      for (int j = 0; j < 4; ++j)
        b[j] = *reinterpret_cast<const short8*>(
            &sW[cw + (wc + j * 16 + r16) * 64 + ks]);
#pragma unroll
      for (int i = 0; i < 2; ++i)
#pragma unroll
        for (int j = 0; j < 4; ++j)
          acc[i][j] = __builtin_amdgcn_mfma_f32_16x16x32_bf16(a[i], b[j],
                                                              acc[i][j], 0, 0, 0);
    }
    // 3. one barrier per iter: implicit vmcnt(0) drains prefetch; all reads
    //    of cur are complete (MFMAs consumed them) -> next iter may overwrite
    __syncthreads();
    cur ^= 1;
  }
  const long long sbase = (MODE == 6) ? (long long)bz * bias_off : 0;
#pragma unroll
  for (int i = 0; i < 2; ++i) {
#pragma unroll
    for (int reg = 0; reg < 4; ++reg) {
      const int n = row0 + wr + i * 16 + q4 * 4 + reg;
      if (n >= N) continue;
      const long long nrow = (long long)n * M;
#pragma unroll
      for (int j = 0; j < 4; ++j) {
        const int m = col0 + wc + j * 16 + r16;
        float v = acc[i][j][reg];
        if (MODE == 0) {
          if (m < 1024) outU[(long long)n * 1024 + m] = f2bf(v + bias[m]);
          else outU2[(long long)n * 1024 + m - 1024] = f2bf(v + bias2[m - 1024]);
        } else if (MODE == 2) {
          outU[nrow + m] = f2bf(v + bias[bias_off + m]);
        } else if (MODE == 3) {
          outU[nrow + m] = f2bf(gelu_f(v + bias[bias_off + m]));
        } else {  // MODE 6: partial slice streaming store
          outF[sbase + nrow + m] = v;
        }
      }
    }
  }
}

// XCD-aware bijective swizzle (m157/m204): hardware assigns workgroup i to
// XCD (i % 8); remap so each XCD owns a CONTIGUOUS logical chunk. Requires
// nwg % 8 == 0 (all GEMM grids here: 512/528/1056/1304).
__device__ __forceinline__ int xcd_swz(int orig, int nwg) {
  return (orig & 7) * (nwg >> 3) + (orig >> 3);
}

template <int MODE>
__global__ __launch_bounds__(256, 3) void mfma_gemm(
    const u16* __restrict__ A, long long a_off, const u16* __restrict__ W,
    int N, int M, int Kd, int klen, int rpb, long long a_bs, long long w_bs,
    const float* __restrict__ bias, const float* __restrict__ bias2, int bias_off,
    u16* __restrict__ outU, u16* __restrict__ outU2, float* __restrict__ outF) {
  __shared__ u16 sA[2 * 64 * 64];
  __shared__ u16 sW[2 * 128 * 64];
  const int gx = gridDim.x, gy = gridDim.y;
  const int nwg = gx * gy * gridDim.z;
  const int orig = blockIdx.x + gx * (blockIdx.y + gy * blockIdx.z);
  const int swz = xcd_swz(orig, nwg);
  const int bx = swz % gx;
  const int t = swz / gx;
  const int by = t % gy;
  const int bz = t / gy;
  gemm_body<MODE>(sA, sW, A, a_off, W, N, M, Kd, klen, rpb, a_bs, w_bs,
                  bias, bias2, bias_off, outU, outU2, outF, bx, by, bz);
}

// ---- fused rqk + qkv GEMM: logical ids [0,512) do rq|rk, [512,1304) do qkv ----
__global__ __launch_bounds__(256, 3) void fused_rqk_qkv(
    const u16* __restrict__ xnorm, const u16* __restrict__ wslot,
    const float* __restrict__ rq_b, const float* __restrict__ rk_b,
    const float* __restrict__ qkv_b,
    u16* __restrict__ qr, u16* __restrict__ kr, u16* __restrict__ qkvb) {
  __shared__ u16 sA[2 * 64 * 64];
  __shared__ u16 sW[2 * 128 * 64];
  const int id = xcd_swz(blockIdx.x, 1304);  // 1304 % 8 == 0, bijective
  if (id < 512) {
    gemm_body<0>(sA, sW, xnorm, 1024LL, wslot,
                 2048, 2048, 1024, 1024, 1024, (long long)S_ * D_, 0LL,
                 rq_b, rk_b, 0, qr, kr, nullptr, id & 15, id >> 4, 0);
  } else {
    const int id2 = id - 512;
    gemm_body<2>(sA, sW, xnorm, 0LL, wslot + (2 << 20),
                 2050, 3072, 1024, 1024, 2050, 0LL, 0LL,
                 qkv_b, nullptr, 0, qkvb, nullptr, nullptr, id2 % 24, id2 / 24, 0);
  }
}

// ---- top-32 with fused slice-reduce: v = s0 + s1 + pos, diag -1e9 ----
__global__ __launch_bounds__(256) void topk_kernel(const float* __restrict__ s0,
                                                   const float* __restrict__ s1,
                                                   const float* __restrict__ pos,
                                                   int* __restrict__ routes,
                                                   float* __restrict__ logw) {
  const int row = blockIdx.x * 4 + (threadIdx.x >> 6);
  const int lane = threadIdx.x & 63;
  const int p = row & (P_ - 1);
  const float* r0 = s0 + (long long)row * P_;
  const float* r1 = s1 + (long long)row * P_;
  const float* pr = pos + (long long)p * P_;
  float v[16];
#pragma unroll
  for (int j = 0; j < 16; ++j) {
    const int q = j * 64 + lane;
    float t = r0[q] + r1[q] + pr[q];
    v[j] = (q == p) ? -1e9f : t;
  }
  float selv = 0.f;
  int seli = 0;
  for (int t = 0; t < K_; ++t) {
    float bv = v[0];
    int bj = 0;
#pragma unroll
    for (int j = 1; j < 16; ++j)
      if (v[j] > bv) { bv = v[j]; bj = j; }
    int bi = bj * 64 + lane;
#pragma unroll
    for (int off = 1; off < 64; off <<= 1) {
      float ov = __shfl_xor(bv, off);
      int oi = __shfl_xor(bi, off);
      if (ov > bv || (ov == bv && oi < bi)) { bv = ov; bi = oi; }
    }
    if (lane == t) { selv = bv; seli = bi; }
    if ((bi & 63) == lane) v[bi >> 6] = -3.0e38f;
  }
  const float sc = selv * (1.0f / TEMP_);
  const float mt = __shfl(sc, 0);
  float e = (lane < K_) ? expf(sc - mt) : 0.f;
  float sum = e;
#pragma unroll
  for (int off = 1; off < 64; off <<= 1) sum += __shfl_xor(sum, off);
  if (lane < K_) {
    const float lw = sc - mt - logf(sum);
    logw[(long long)row * K_ + lane] = fmaxf(lw, -10.0f);
    routes[(long long)row * K_ + lane] = seli;
  }
}

// ---- cls attention phase 1: grid (NS_, B*H); chunked online stats ----
__global__ __launch_bounds__(256) void attn_cls_p1(const u16* __restrict__ qkv,
                                                   float* __restrict__ part) {
  __shared__ float qs[HD_];
  __shared__ float lg[65];
  __shared__ float red4[4];
  __shared__ float sacc[4][HD_];
  const int ck = blockIdx.x;
  const int bh = blockIdx.y;
  const int b = bh >> 4, h = bh & 15;
  const int tid = threadIdx.x;
  const int lane = tid & 63;
  const int wv = tid >> 6;
  const int s0 = ck * 65;
  const int rows = min(65, S_ - s0);
  const long long base = (long long)b * S_ * 3072;
  if (tid < HD_) qs[tid] = bf2f(qkv[base + h * HD_ + tid]);
  __syncthreads();
  float lmax = -3.0e38f;
  if (tid < rows) {
    const u16* kp = qkv + base + (long long)(s0 + tid) * 3072 + 1024 + h * HD_;
    float d = 0.f;
#pragma unroll
    for (int c = 0; c < 8; ++c) {
      short8 kv = *reinterpret_cast<const short8*>(kp + c * 8);
#pragma unroll
      for (int e = 0; e < 8; ++e) d += qs[c * 8 + e] * bf2f((u16)kv[e]);
    }
    d *= SCALE_;
    lg[tid] = d;
    lmax = d;
  }
  const float m = block_max256(lmax, red4);
  float e = 0.f;
  if (tid < rows) {
    e = expf(lg[tid] - m);
    lg[tid] = e;
  }
  const float l = block_sum256(e, red4);
  __syncthreads();
  float acc = 0.f;
  for (int r = wv; r < rows; r += 4)
    acc += lg[r] * bf2f(qkv[base + (long long)(s0 + r) * 3072 + 2048 + h * HD_ + lane]);
  sacc[wv][lane] = acc;
  __syncthreads();
  float* pc = part + ((long long)bh * NS_ + ck) * 66;
  if (tid < HD_)
    pc[tid] = sacc[0][tid] + sacc[1][tid] + sacc[2][tid] + sacc[3][tid];
  if (tid == 64) pc[64] = m;
  if (tid == 65) pc[65] = l;
}

// ---- cls attention phase 2: combine; one block (64 thr) per (b,h) ----
__global__ __launch_bounds__(64) void attn_cls_p2(const float* __restrict__ part,
                                                  u16* __restrict__ out) {
  const int bh = blockIdx.x;
  const int b = bh >> 4, h = bh & 15;
  const int tid = threadIdx.x;
  const float* pb = part + (long long)bh * NS_ * 66;
  float M = -3.0e38f;
#pragma unroll
  for (int c = 0; c < NS_; ++c) M = fmaxf(M, pb[c * 66 + 64]);
  float L = 0.f, a = 0.f;
#pragma unroll
  for (int c = 0; c < NS_; ++c) {
    const float w = expf(pb[c * 66 + 64] - M);
    L += pb[c * 66 + 65] * w;
    a += pb[c * 66 + tid] * w;
  }
  out[(long long)b * S_ * D_ + h * HD_ + tid] = f2bf(a / L);
}

// ---- routed patch attention: one wave per (b,p,h) ----
__global__ __launch_bounds__(64) void attn_patch_kernel(const u16* __restrict__ qkv,
                                                        const int* __restrict__ routes,
                                                        const float* __restrict__ logw,
                                                        u16* __restrict__ out) {
  __shared__ float qs[HD_];
  __shared__ float wk[K_];
  __shared__ int sidx[K_];
  const int bid = blockIdx.x;
  const int h = bid & 15;
  const int p = (bid >> 4) & (P_ - 1);
  const int b = bid >> 14;
  const int tid = threadIdx.x;
  const long long base = (long long)b * S_ * 3072;
  qs[tid] = bf2f(qkv[base + (long long)(1 + p) * 3072 + h * HD_ + tid]);
  __syncthreads();
  float lg = -3.0e38f;
  if (tid < K_) {
    const long long ro = ((long long)(b * P_ + p)) * K_ + tid;
    const int r = routes[ro];
    sidx[tid] = r;
    const u16* kp = qkv + base + (long long)(1 + r) * 3072 + 1024 + h * HD_;
    float d = 0.f;
#pragma unroll
    for (int c = 0; c < 8; ++c) {
      short8 kv = *reinterpret_cast<const short8*>(kp + c * 8);
#pragma unroll
      for (int e = 0; e < 8; ++e) d += qs[c * 8 + e] * bf2f((u16)kv[e]);
    }
    lg = d * SCALE_ + logw[ro];
  }
  float m = lg;
#pragma unroll
  for (int off = 1; off < 32; off <<= 1) m = fmaxf(m, __shfl_xor(m, off));
  float e = (tid < K_) ? expf(lg - m) : 0.f;
  float sum = e;
#pragma unroll
  for (int off = 1; off < 32; off <<= 1) sum += __shfl_xor(sum, off);
  if (tid < K_) wk[tid] = e / sum;
  __syncthreads();
  float acc = 0.f;
#pragma unroll 4
  for (int k = 0; k < K_; ++k)
    acc += wk[k] * bf2f(qkv[base + (long long)(1 + sidx[k]) * 3072 + 2048 + h * HD_ + tid]);
  out[((long long)b * S_ + 1 + p) * D_ + h * HD_ + tid] = f2bf(acc);
}

extern "C" void kernel_launch(void* const* d_in, const int* in_sizes, int n_in,
                              void* d_out, int out_size, void* d_ws, size_t ws_size,
                              hipStream_t stream) {
  const float* x      = (const float*)d_in[0];
  const float* n1w    = (const float*)d_in[1];
  const float* n1b    = (const float*)d_in[2];
  const float* rq_w   = (const float*)d_in[3];
  const float* rq_b   = (const float*)d_in[4];
  const float* rk_w   = (const float*)d_in[5];
  const float* rk_b   = (const float*)d_in[6];
  const float* pos    = (const float*)d_in[7];
  const float* qkv_w  = (const float*)d_in[8];
  const float* qkv_b  = (const float*)d_in[9];
  const float* proj_w = (const float*)d_in[10];
  const float* proj_b = (const float*)d_in[11];
  const float* n2w    = (const float*)d_in[12];
  const float* n2b    = (const float*)d_in[13];
  const float* fc1_w  = (const float*)d_in[14];
  const float* fc1_b  = (const float*)d_in[15];
  const float* fc2_w  = (const float*)d_in[16];
  const float* fc2_b  = (const float*)d_in[17];
  float* out = (float*)d_out;

  // ---- workspace layout (bytes; ~51.2 MB; evidence: ws >= 59.3 MB) ----
  // Base slots (phase 1):
  char* mem = (char*)d_ws;
  int*   routes = (int*)mem;                        //   262,144
  float* logw   = (float*)(mem + 262144);           //   262,144
  float* part   = (float*)(mem + 524288);           //   262,144
  u16*   wslot  = (u16*)(mem + 786432);             // 16,777,216 (8M elems)
  u16*   xnorm  = (u16*)(mem + 17563648);           //  4,198,400
  u16*   qr     = (u16*)(mem + 21762048);           //  4,198,400 (qr, later attn)
  u16*   attn   = qr;
  u16*   qkvb   = (u16*)(mem + 25960448);           // 12,595,200
  u16*   kr     = (u16*)(mem + 38555648);           //  4,202,496
  u16*   hbuf   = qkvb;                             // spans qkvb+kr (16.8 MB), live fc1->fc2
  float* x1     = (float*)(mem + 42758144);         //  8,396,800
  // Split-K partial-slice overlays (each target dead at write time; verified
  // dispatch-by-dispatch in r10/r11 aliasing audit):
  //  scores: p0 over dead rq/rk/qkv weights; p1 over scores/x1 slot (pre-x1)
  float* sc_p0 = (float*)(mem + 786432);            // stride 10,492,928 floats
  float* sc_p1 = (float*)(mem + 42758144);
  //  proj:   p0/p1 over dead qkvb+kr (after attn); consumed by ln2res
  float* pr_p0 = (float*)(mem + 25960448);          // stride 2,099,200 floats
  float* pr_p1 = (float*)(mem + 34357248);
  //  fc2:    p0 over dead routes/logw/part + fc1 weights (after fc1);
  //          p1 over dead xnorm+attn; consumed by fc2red
  float* fc_p0 = (float*)(mem + 0);                 // stride 4,390,912 floats
  float* fc_p1 = (float*)(mem + 17563648);

  // 1. LN1: x -> xnorm (bf16)
  ln_kernel<<<B_ * S_, 256, 0, stream>>>(x, n1w, n1b, xnorm);

  // 2. convert rq|rk|qkv|proj weights (all contiguous) into wslot [0:6M)
  conv4_kernel<<<6144, 256, 0, stream>>>(rq_w, 1 << 20, rk_w, 1 << 20,
                                         qkv_w, 3 << 20, proj_w, 1 << 20, wslot);

  // 3. fused rqk + qkv GEMM (1304 blocks, XCD-swizzled)
  fused_rqk_qkv<<<1304, 256, 0, stream>>>(xnorm, wslot, rq_b, rk_b, qkv_b,
                                          qr, kr, qkvb);

  // 4. l2norm qr and kr in one launch
  l2norm2_kernel<<<4096, 256, 0, stream>>>(qr, kr);

  // 5. scores split-K x2 -> partial slices (streaming stores, no atomics)
  mfma_gemm<6><<<dim3(8, 32, 2), 256, 0, stream>>>(qr, 0LL, kr,
      2048, 1024, 1024, 512, 1024, 1LL << 20, 1LL << 20,
      nullptr, nullptr, 10492928, nullptr, nullptr, sc_p0);

  // 6. top-32 routing with fused slice-reduce (+pos, diag)
  topk_kernel<<<512, 256, 0, stream>>>(sc_p0, sc_p1, pos, routes, logw);

  // 7. attention -> attn (bf16)
  attn_cls_p1<<<dim3(NS_, B_ * H_), 256, 0, stream>>>(qkvb, part);
  attn_cls_p2<<<B_ * H_, 64, 0, stream>>>(part, attn);
  attn_patch_kernel<<<B_ * P_ * H_, 64, 0, stream>>>(qkvb, routes, logw, attn);

  // 8. proj split-K x2 -> partial slices
  mfma_gemm<6><<<dim3(8, 33, 2), 256, 0, stream>>>(attn, 0LL, wslot + (5 << 20),
      2050, 1024, 1024, 512, 2050, 0LL, 0LL,
      nullptr, nullptr, 2099200, nullptr, nullptr, pr_p0);

  // 9. convert fc1|fc2 weights into wslot [0:8M) (old weights dead)
  conv4_kernel<<<8192, 256, 0, stream>>>(fc1_w, 1 << 22, fc2_w, 1 << 22,
                                         nullptr, 0, nullptr, 0, wslot);

  // 10. fused residual+LN2: x1 = x + proj_b + p0 + p1; xnorm = LN(x1)
  ln2res_kernel<<<B_ * S_, 256, 0, stream>>>(x, proj_b, pr_p0, pr_p1,
                                             n2w, n2b, x1, xnorm);

  // 11. MLP: fc1 -> hbuf (bf16, gelu); fc2 split-K x2 -> partial slices;
  //     final fused reduce out = x1 + fc2_b + p0 + p1
  mfma_gemm<3><<<dim3(32, 33), 256, 0, stream>>>(xnorm, 0LL, wslot,
      2050, 4096, 1024, 1024, 2050, 0LL, 0LL,
      fc1_b, nullptr, 0, hbuf, nullptr, nullptr);
  mfma_gemm<6><<<dim3(8, 33, 2), 256, 0, stream>>>(hbuf, 0LL, wslot + (1 << 22),
      2050, 1024, 4096, 2048, 2050, 0LL, 0LL,
      nullptr, nullptr, 4390912, nullptr, nullptr, fc_p0);
  fc2red_kernel<<<B_ * S_, 256, 0, stream>>>(x1, fc2_b, fc_p0, fc_p1, out);
}

// Round 16
// 376.535 us; speedup vs baseline: 1.0321x; 1.0321x over previous
//
#include <hip/hip_runtime.h>
#include <hip/hip_bf16.h>
#include <math.h>

typedef unsigned short u16;
typedef __attribute__((ext_vector_type(8))) short short8;
typedef __attribute__((ext_vector_type(4))) float f32x4;

#define B_ 2
#define S_ 1025
#define D_ 1024
#define H_ 16
#define HD_ 64
#define P_ 1024
#define K_ 32
#define NS_ 16   // attn_cls S-splits

static constexpr float TEMP_ = 0.1f;
static constexpr float SCALE_ = 0.125f;
static constexpr float EPS_LN_ = 1e-5f;

__device__ __forceinline__ float bf2f(u16 u) {
  unsigned int t = ((unsigned int)u) << 16;
  float f;
  __builtin_memcpy(&f, &t, 4);
  return f;
}
__device__ __forceinline__ u16 f2bf(float f) {
  __hip_bfloat16 h = __float2bfloat16(f);
  u16 u;
  __builtin_memcpy(&u, &h, 2);
  return u;
}
__device__ __forceinline__ float gelu_f(float x) {
  return 0.5f * x * (1.0f + erff(x * 0.70710678118654752f));
}

typedef __attribute__((address_space(1))) const unsigned int gas_u32;
typedef __attribute__((address_space(3))) unsigned int las_u32;
__device__ __forceinline__ void g2l16(const void* g, void* l) {
  __builtin_amdgcn_global_load_lds((gas_u32*)g, (las_u32*)l, 16, 0, 0);
}

// ---- fused flat f32->bf16 convert of up to 4 contiguous tensors ----
__global__ __launch_bounds__(256) void conv4_kernel(
    const float* __restrict__ s0, int n0, const float* __restrict__ s1, int n1,
    const float* __restrict__ s2, int n2, const float* __restrict__ s3, int n3,
    u16* __restrict__ dst) {
  const int e = (blockIdx.x * 256 + threadIdx.x) * 4;
  const float* src;
  int off;
  if (e < n0) { src = s0; off = e; }
  else if (e < n0 + n1) { src = s1; off = e - n0; }
  else if (e < n0 + n1 + n2) { src = s2; off = e - n0 - n1; }
  else if (e < n0 + n1 + n2 + n3) { src = s3; off = e - n0 - n1 - n2; }
  else return;
  float4 t = *reinterpret_cast<const float4*>(src + off);
  ushort4 o;
  o.x = f2bf(t.x); o.y = f2bf(t.y); o.z = f2bf(t.z); o.w = f2bf(t.w);
  *reinterpret_cast<ushort4*>(dst + e) = o;
}

// ---- block reductions (256 threads) ----
__device__ __forceinline__ float block_sum256(float v, float* red4) {
  for (int off = 32; off > 0; off >>= 1) v += __shfl_down(v, off);
  if ((threadIdx.x & 63) == 0) red4[threadIdx.x >> 6] = v;
  __syncthreads();
  float r = red4[0] + red4[1] + red4[2] + red4[3];
  __syncthreads();
  return r;
}
__device__ __forceinline__ float block_max256(float v, float* red4) {
  for (int off = 32; off > 0; off >>= 1) v = fmaxf(v, __shfl_down(v, off));
  if ((threadIdx.x & 63) == 0) red4[threadIdx.x >> 6] = v;
  __syncthreads();
  float r = fmaxf(fmaxf(red4[0], red4[1]), fmaxf(red4[2], red4[3]));
  __syncthreads();
  return r;
}

// ---- LayerNorm f32 in -> bf16 out ----
__global__ __launch_bounds__(256) void ln_kernel(const float* __restrict__ x,
                                                 const float* __restrict__ w,
                                                 const float* __restrict__ b,
                                                 u16* __restrict__ out) {
  __shared__ float red4[4];
  const long long base = (long long)blockIdx.x * D_;
  float v[4];
  float s = 0.f, ss = 0.f;
#pragma unroll
  for (int u = 0; u < 4; ++u) {
    int d = threadIdx.x + u * 256;
    float f = x[base + d];
    v[u] = f; s += f; ss += f * f;
  }
  float tot = block_sum256(s, red4);
  float tot2 = block_sum256(ss, red4);
  float mean = tot * (1.0f / D_);
  float var = tot2 * (1.0f / D_) - mean * mean;
  float rstd = rsqrtf(var + EPS_LN_);
#pragma unroll
  for (int u = 0; u < 4; ++u) {
    int d = threadIdx.x + u * 256;
    out[base + d] = f2bf((v[u] - mean) * rstd * w[d] + b[d]);
  }
}

// ---- fused residual + LN2: x1 = x + proj_b + p0 + p1; xnorm = LN(x1) ----
__global__ __launch_bounds__(256) void ln2res_kernel(
    const float* __restrict__ x, const float* __restrict__ pb,
    const float* __restrict__ p0, const float* __restrict__ p1,
    const float* __restrict__ w, const float* __restrict__ b,
    float* __restrict__ x1, u16* __restrict__ out) {
  __shared__ float red4[4];
  const long long base = (long long)blockIdx.x * D_;
  float v[4];
  float s = 0.f, ss = 0.f;
#pragma unroll
  for (int u = 0; u < 4; ++u) {
    int d = threadIdx.x + u * 256;
    float f = x[base + d] + pb[d] + p0[base + d] + p1[base + d];
    x1[base + d] = f;
    v[u] = f; s += f; ss += f * f;
  }
  float tot = block_sum256(s, red4);
  float tot2 = block_sum256(ss, red4);
  float mean = tot * (1.0f / D_);
  float var = tot2 * (1.0f / D_) - mean * mean;
  float rstd = rsqrtf(var + EPS_LN_);
#pragma unroll
  for (int u = 0; u < 4; ++u) {
    int d = threadIdx.x + u * 256;
    out[base + d] = f2bf((v[u] - mean) * rstd * w[d] + b[d]);
  }
}

// ---- final fused reduce: out = x1 + fc2_b + p0 + p1 ----
__global__ __launch_bounds__(256) void fc2red_kernel(
    const float* __restrict__ x1, const float* __restrict__ b,
    const float* __restrict__ p0, const float* __restrict__ p1,
    float* __restrict__ out) {
  const long long base = (long long)blockIdx.x * D_;
#pragma unroll
  for (int u = 0; u < 4; ++u) {
    int d = threadIdx.x + u * 256;
    out[base + d] = x1[base + d] + b[d] + p0[base + d] + p1[base + d];
  }
}

// ---- L2 normalize qr then kr rows in one launch (4096 blocks) ----
__global__ __launch_bounds__(256) void l2norm2_kernel(u16* __restrict__ qr,
                                                      u16* __restrict__ kr) {
  __shared__ float red4[4];
  const int row = blockIdx.x;
  u16* x = (row < 2048) ? qr + (long long)row * D_
                        : kr + (long long)(row - 2048) * D_;
  float v[4];
  float ss = 0.f;
#pragma unroll
  for (int u = 0; u < 4; ++u) {
    int d = threadIdx.x + u * 256;
    v[u] = bf2f(x[d]);
    ss += v[u] * v[u];
  }
  float tot = block_sum256(ss, red4);
  float inv = 1.0f / fmaxf(sqrtf(tot), 1e-12f);
#pragma unroll
  for (int u = 0; u < 4; ++u) {
    int d = threadIdx.x + u * 256;
    x[d] = f2bf(v[u] * inv);
  }
}

// ---- MFMA GEMM body: out[n,m] = sum_k A[n,k]*W[m,k], 64x128 tile, BK=64 ----
// REVERTED to the r13-measured single-buffer form (383.5 us best). Ledger:
//  r3  counted-vmcnt dbuf      REGRESSED (+34 us)  -- compiler re-orders
//  r7  deeper split-K          REGRESSED (+39 us)  -- atomic RMW tax
//  r8  XCD swizzle             KEPT (FETCH -76%, dur -3%)
//  r10 64x128 tile             NULL (kept: same perf, less LDS)
//  r13 atomic-free split-K     WIN  (-20.5 us)     -- MODE 6 + fused consumers
//  r15 1-barrier prefetch dbuf REGRESSED (+5 us)   -- __syncthreads forces
//      vmcnt(0) drain at the barrier regardless; only ~1 tile of compute to
//      hide under; paid 2x LDS + 28 VGPR + addr-calc VALU (12->27%).
//  => Source-level pipelining of this 2-barrier structure is CLOSED (both
//     variants measured). Path past it = full 8-phase schedule (new sync
//     template, race-screen required; not attempted headless).
// Staging: A 2 chunks + W 4 chunks of (32 rows x 64 k); k granules (16B)
// XOR-swizzled by (row&7) on the GLOBAL src addr -> ds_read conflict-free
// (r2/r8/r10/r13 verified: SQ_LDS_BANK_CONFLICT = 0).
// MODE 0: RQK : m<1024 -> outU=bf16(v+bias[m]); else outU2=bf16(v+bias2[m-1024])
// MODE 2: BIAS: outU = bf16(v + bias[bias_off+m])
// MODE 3: GELU: outU = bf16(gelu(v + bias[bias_off+m]))
// MODE 6: PART: outF[bz*bias_off + n*M + m] = v  (bias_off = slice stride, floats)
template <int MODE>
__device__ __forceinline__ void gemm_body(
    u16* sA, u16* sW,
    const u16* __restrict__ A, long long a_off, const u16* __restrict__ W,
    int N, int M, int Kd, int klen, int rpb, long long a_bs, long long w_bs,
    const float* __restrict__ bias, const float* __restrict__ bias2, int bias_off,
    u16* __restrict__ outU, u16* __restrict__ outU2, float* __restrict__ outF,
    int bx, int by, int bz) {
  const int tid = threadIdx.x;
  const int lane = tid & 63;
  const int q4 = lane >> 4;
  const int r16 = lane & 15;
  const int wave = tid >> 6;
  const int wr = (wave & 1) * 32;   // wave row-group: 2 x 32 rows
  const int wc = (wave >> 1) * 64;  // wave col-group: 2 x 64 cols
  const int row0 = by * 64;
  const int col0 = bx * 128;
  const int batch = row0 / rpb;
  const u16* Ab = A + a_off + (long long)batch * a_bs +
                  (long long)(row0 - batch * rpb) * Kd;
  const u16* Wb = W + (long long)batch * w_bs + (long long)col0 * Kd;
  const int rmax = N - 1 - row0;
  // staging: chunks of (32 rows x 64 k); lds dest = c*2048 + tid*8 (u16)
  const int srow = tid >> 3;                     // row within chunk (0..31)
  const int kx = ((tid & 7) ^ (srow & 7)) * 8;   // swizzled global k-granule
  const int kbeg = bz * klen;
  const int niter = klen >> 6;
  f32x4 acc[2][4] = {};
  for (int it = 0; it < niter; ++it) {
    const int k0 = kbeg + it * 64;
#pragma unroll
    for (int c = 0; c < 2; ++c) {
      const int rg = c * 32 + srow;
      g2l16(Ab + (long long)min(rg, rmax) * Kd + kx + k0, &sA[c * 2048 + tid * 8]);
    }
#pragma unroll
    for (int c = 0; c < 4; ++c) {
      const int rg = c * 32 + srow;
      g2l16(Wb + (long long)rg * Kd + kx + k0, &sW[c * 2048 + tid * 8]);
    }
    __builtin_amdgcn_s_waitcnt(0);
    __syncthreads();
#pragma unroll
    for (int s = 0; s < 2; ++s) {
      short8 a[2], b[4];
      const int ks = ((s * 4 + q4) ^ (r16 & 7)) * 8;
#pragma unroll
      for (int i = 0; i < 2; ++i)
        a[i] = *reinterpret_cast<const short8*>(&sA[(wr + i * 16 + r16) * 64 + ks]);
#pragma unroll
      for (int j = 0; j < 4; ++j)
        b[j] = *reinterpret_cast<const short8*>(&sW[(wc + j * 16 + r16) * 64 + ks]);
#pragma unroll
      for (int i = 0; i < 2; ++i)
#pragma unroll
        for (int j = 0; j < 4; ++j)
          acc[i][j] = __builtin_amdgcn_mfma_f32_16x16x32_bf16(a[i], b[j],
                                                              acc[i][j], 0, 0, 0);
    }
    __syncthreads();
  }
  const long long sbase = (MODE == 6) ? (long long)bz * bias_off : 0;
#pragma unroll
  for (int i = 0; i < 2; ++i) {
#pragma unroll
    for (int reg = 0; reg < 4; ++reg) {
      const int n = row0 + wr + i * 16 + q4 * 4 + reg;
      if (n >= N) continue;
      const long long nrow = (long long)n * M;
#pragma unroll
      for (int j = 0; j < 4; ++j) {
        const int m = col0 + wc + j * 16 + r16;
        float v = acc[i][j][reg];
        if (MODE == 0) {
          if (m < 1024) outU[(long long)n * 1024 + m] = f2bf(v + bias[m]);
          else outU2[(long long)n * 1024 + m - 1024] = f2bf(v + bias2[m - 1024]);
        } else if (MODE == 2) {
          outU[nrow + m] = f2bf(v + bias[bias_off + m]);
        } else if (MODE == 3) {
          outU[nrow + m] = f2bf(gelu_f(v + bias[bias_off + m]));
        } else {  // MODE 6: partial slice streaming store
          outF[sbase + nrow + m] = v;
        }
      }
    }
  }
}

// XCD-aware bijective swizzle (m157/m204): hardware assigns workgroup i to
// XCD (i % 8); remap so each XCD owns a CONTIGUOUS logical chunk. Requires
// nwg % 8 == 0 (all GEMM grids here: 512/528/1056/1304).
__device__ __forceinline__ int xcd_swz(int orig, int nwg) {
  return (orig & 7) * (nwg >> 3) + (orig >> 3);
}

template <int MODE>
__global__ __launch_bounds__(256, 6) void mfma_gemm(
    const u16* __restrict__ A, long long a_off, const u16* __restrict__ W,
    int N, int M, int Kd, int klen, int rpb, long long a_bs, long long w_bs,
    const float* __restrict__ bias, const float* __restrict__ bias2, int bias_off,
    u16* __restrict__ outU, u16* __restrict__ outU2, float* __restrict__ outF) {
  __shared__ u16 sA[64 * 64];
  __shared__ u16 sW[128 * 64];
  const int gx = gridDim.x, gy = gridDim.y;
  const int nwg = gx * gy * gridDim.z;
  const int orig = blockIdx.x + gx * (blockIdx.y + gy * blockIdx.z);
  const int swz = xcd_swz(orig, nwg);
  const int bx = swz % gx;
  const int t = swz / gx;
  const int by = t % gy;
  const int bz = t / gy;
  gemm_body<MODE>(sA, sW, A, a_off, W, N, M, Kd, klen, rpb, a_bs, w_bs,
                  bias, bias2, bias_off, outU, outU2, outF, bx, by, bz);
}

// ---- fused rqk + qkv GEMM: logical ids [0,512) do rq|rk, [512,1304) do qkv ----
__global__ __launch_bounds__(256, 6) void fused_rqk_qkv(
    const u16* __restrict__ xnorm, const u16* __restrict__ wslot,
    const float* __restrict__ rq_b, const float* __restrict__ rk_b,
    const float* __restrict__ qkv_b,
    u16* __restrict__ qr, u16* __restrict__ kr, u16* __restrict__ qkvb) {
  __shared__ u16 sA[64 * 64];
  __shared__ u16 sW[128 * 64];
  const int id = xcd_swz(blockIdx.x, 1304);  // 1304 % 8 == 0, bijective
  if (id < 512) {
    gemm_body<0>(sA, sW, xnorm, 1024LL, wslot,
                 2048, 2048, 1024, 1024, 1024, (long long)S_ * D_, 0LL,
                 rq_b, rk_b, 0, qr, kr, nullptr, id & 15, id >> 4, 0);
  } else {
    const int id2 = id - 512;
    gemm_body<2>(sA, sW, xnorm, 0LL, wslot + (2 << 20),
                 2050, 3072, 1024, 1024, 2050, 0LL, 0LL,
                 qkv_b, nullptr, 0, qkvb, nullptr, nullptr, id2 % 24, id2 / 24, 0);
  }
}

// ---- top-32 with fused slice-reduce: v = s0 + s1 + pos, diag -1e9 ----
__global__ __launch_bounds__(256) void topk_kernel(const float* __restrict__ s0,
                                                   const float* __restrict__ s1,
                                                   const float* __restrict__ pos,
                                                   int* __restrict__ routes,
                                                   float* __restrict__ logw) {
  const int row = blockIdx.x * 4 + (threadIdx.x >> 6);
  const int lane = threadIdx.x & 63;
  const int p = row & (P_ - 1);
  const float* r0 = s0 + (long long)row * P_;
  const float* r1 = s1 + (long long)row * P_;
  const float* pr = pos + (long long)p * P_;
  float v[16];
#pragma unroll
  for (int j = 0; j < 16; ++j) {
    const int q = j * 64 + lane;
    float t = r0[q] + r1[q] + pr[q];
    v[j] = (q == p) ? -1e9f : t;
  }
  float selv = 0.f;
  int seli = 0;
  for (int t = 0; t < K_; ++t) {
    float bv = v[0];
    int bj = 0;
#pragma unroll
    for (int j = 1; j < 16; ++j)
      if (v[j] > bv) { bv = v[j]; bj = j; }
    int bi = bj * 64 + lane;
#pragma unroll
    for (int off = 1; off < 64; off <<= 1) {
      float ov = __shfl_xor(bv, off);
      int oi = __shfl_xor(bi, off);
      if (ov > bv || (ov == bv && oi < bi)) { bv = ov; bi = oi; }
    }
    if (lane == t) { selv = bv; seli = bi; }
    if ((bi & 63) == lane) v[bi >> 6] = -3.0e38f;
  }
  const float sc = selv * (1.0f / TEMP_);
  const float mt = __shfl(sc, 0);
  float e = (lane < K_) ? expf(sc - mt) : 0.f;
  float sum = e;
#pragma unroll
  for (int off = 1; off < 64; off <<= 1) sum += __shfl_xor(sum, off);
  if (lane < K_) {
    const float lw = sc - mt - logf(sum);
    logw[(long long)row * K_ + lane] = fmaxf(lw, -10.0f);
    routes[(long long)row * K_ + lane] = seli;
  }
}

// ---- cls attention phase 1: grid (NS_, B*H); chunked online stats ----
__global__ __launch_bounds__(256) void attn_cls_p1(const u16* __restrict__ qkv,
                                                   float* __restrict__ part) {
  __shared__ float qs[HD_];
  __shared__ float lg[65];
  __shared__ float red4[4];
  __shared__ float sacc[4][HD_];
  const int ck = blockIdx.x;
  const int bh = blockIdx.y;
  const int b = bh >> 4, h = bh & 15;
  const int tid = threadIdx.x;
  const int lane = tid & 63;
  const int wv = tid >> 6;
  const int s0 = ck * 65;
  const int rows = min(65, S_ - s0);
  const long long base = (long long)b * S_ * 3072;
  if (tid < HD_) qs[tid] = bf2f(qkv[base + h * HD_ + tid]);
  __syncthreads();
  float lmax = -3.0e38f;
  if (tid < rows) {
    const u16* kp = qkv + base + (long long)(s0 + tid) * 3072 + 1024 + h * HD_;
    float d = 0.f;
#pragma unroll
    for (int c = 0; c < 8; ++c) {
      short8 kv = *reinterpret_cast<const short8*>(kp + c * 8);
#pragma unroll
      for (int e = 0; e < 8; ++e) d += qs[c * 8 + e] * bf2f((u16)kv[e]);
    }
    d *= SCALE_;
    lg[tid] = d;
    lmax = d;
  }
  const float m = block_max256(lmax, red4);
  float e = 0.f;
  if (tid < rows) {
    e = expf(lg[tid] - m);
    lg[tid] = e;
  }
  const float l = block_sum256(e, red4);
  __syncthreads();
  float acc = 0.f;
  for (int r = wv; r < rows; r += 4)
    acc += lg[r] * bf2f(qkv[base + (long long)(s0 + r) * 3072 + 2048 + h * HD_ + lane]);
  sacc[wv][lane] = acc;
  __syncthreads();
  float* pc = part + ((long long)bh * NS_ + ck) * 66;
  if (tid < HD_)
    pc[tid] = sacc[0][tid] + sacc[1][tid] + sacc[2][tid] + sacc[3][tid];
  if (tid == 64) pc[64] = m;
  if (tid == 65) pc[65] = l;
}

// ---- cls attention phase 2: combine; one block (64 thr) per (b,h) ----
__global__ __launch_bounds__(64) void attn_cls_p2(const float* __restrict__ part,
                                                  u16* __restrict__ out) {
  const int bh = blockIdx.x;
  const int b = bh >> 4, h = bh & 15;
  const int tid = threadIdx.x;
  const float* pb = part + (long long)bh * NS_ * 66;
  float M = -3.0e38f;
#pragma unroll
  for (int c = 0; c < NS_; ++c) M = fmaxf(M, pb[c * 66 + 64]);
  float L = 0.f, a = 0.f;
#pragma unroll
  for (int c = 0; c < NS_; ++c) {
    const float w = expf(pb[c * 66 + 64] - M);
    L += pb[c * 66 + 65] * w;
    a += pb[c * 66 + tid] * w;
  }
  out[(long long)b * S_ * D_ + h * HD_ + tid] = f2bf(a / L);
}

// ---- routed patch attention: one wave per (b,p,h) ----
__global__ __launch_bounds__(64) void attn_patch_kernel(const u16* __restrict__ qkv,
                                                        const int* __restrict__ routes,
                                                        const float* __restrict__ logw,
                                                        u16* __restrict__ out) {
  __shared__ float qs[HD_];
  __shared__ float wk[K_];
  __shared__ int sidx[K_];
  const int bid = blockIdx.x;
  const int h = bid & 15;
  const int p = (bid >> 4) & (P_ - 1);
  const int b = bid >> 14;
  const int tid = threadIdx.x;
  const long long base = (long long)b * S_ * 3072;
  qs[tid] = bf2f(qkv[base + (long long)(1 + p) * 3072 + h * HD_ + tid]);
  __syncthreads();
  float lg = -3.0e38f;
  if (tid < K_) {
    const long long ro = ((long long)(b * P_ + p)) * K_ + tid;
    const int r = routes[ro];
    sidx[tid] = r;
    const u16* kp = qkv + base + (long long)(1 + r) * 3072 + 1024 + h * HD_;
    float d = 0.f;
#pragma unroll
    for (int c = 0; c < 8; ++c) {
      short8 kv = *reinterpret_cast<const short8*>(kp + c * 8);
#pragma unroll
      for (int e = 0; e < 8; ++e) d += qs[c * 8 + e] * bf2f((u16)kv[e]);
    }
    lg = d * SCALE_ + logw[ro];
  }
  float m = lg;
#pragma unroll
  for (int off = 1; off < 32; off <<= 1) m = fmaxf(m, __shfl_xor(m, off));
  float e = (tid < K_) ? expf(lg - m) : 0.f;
  float sum = e;
#pragma unroll
  for (int off = 1; off < 32; off <<= 1) sum += __shfl_xor(sum, off);
  if (tid < K_) wk[tid] = e / sum;
  __syncthreads();
  float acc = 0.f;
#pragma unroll 4
  for (int k = 0; k < K_; ++k)
    acc += wk[k] * bf2f(qkv[base + (long long)(1 + sidx[k]) * 3072 + 2048 + h * HD_ + tid]);
  out[((long long)b * S_ + 1 + p) * D_ + h * HD_ + tid] = f2bf(acc);
}

extern "C" void kernel_launch(void* const* d_in, const int* in_sizes, int n_in,
                              void* d_out, int out_size, void* d_ws, size_t ws_size,
                              hipStream_t stream) {
  const float* x      = (const float*)d_in[0];
  const float* n1w    = (const float*)d_in[1];
  const float* n1b    = (const float*)d_in[2];
  const float* rq_w   = (const float*)d_in[3];
  const float* rq_b   = (const float*)d_in[4];
  const float* rk_w   = (const float*)d_in[5];
  const float* rk_b   = (const float*)d_in[6];
  const float* pos    = (const float*)d_in[7];
  const float* qkv_w  = (const float*)d_in[8];
  const float* qkv_b  = (const float*)d_in[9];
  const float* proj_w = (const float*)d_in[10];
  const float* proj_b = (const float*)d_in[11];
  const float* n2w    = (const float*)d_in[12];
  const float* n2b    = (const float*)d_in[13];
  const float* fc1_w  = (const float*)d_in[14];
  const float* fc1_b  = (const float*)d_in[15];
  const float* fc2_w  = (const float*)d_in[16];
  const float* fc2_b  = (const float*)d_in[17];
  float* out = (float*)d_out;

  // ---- workspace layout (bytes; ~51.2 MB; evidence: ws >= 59.3 MB) ----
  // Base slots (phase 1):
  char* mem = (char*)d_ws;
  int*   routes = (int*)mem;                        //   262,144
  float* logw   = (float*)(mem + 262144);           //   262,144
  float* part   = (float*)(mem + 524288);           //   262,144
  u16*   wslot  = (u16*)(mem + 786432);             // 16,777,216 (8M elems)
  u16*   xnorm  = (u16*)(mem + 17563648);           //  4,198,400
  u16*   qr     = (u16*)(mem + 21762048);           //  4,198,400 (qr, later attn)
  u16*   attn   = qr;
  u16*   qkvb   = (u16*)(mem + 25960448);           // 12,595,200
  u16*   kr     = (u16*)(mem + 38555648);           //  4,202,496
  u16*   hbuf   = qkvb;                             // spans qkvb+kr (16.8 MB), live fc1->fc2
  float* x1     = (float*)(mem + 42758144);         //  8,396,800
  // Split-K partial-slice overlays (each target dead at write time; verified
  // dispatch-by-dispatch in r10/r11 aliasing audit):
  //  scores: p0 over dead rq/rk/qkv weights; p1 over scores/x1 slot (pre-x1)
  float* sc_p0 = (float*)(mem + 786432);            // stride 10,492,928 floats
  float* sc_p1 = (float*)(mem + 42758144);
  //  proj:   p0/p1 over dead qkvb+kr (after attn); consumed by ln2res
  float* pr_p0 = (float*)(mem + 25960448);          // stride 2,099,200 floats
  float* pr_p1 = (float*)(mem + 34357248);
  //  fc2:    p0 over dead routes/logw/part + fc1 weights (after fc1);
  //          p1 over dead xnorm+attn; consumed by fc2red
  float* fc_p0 = (float*)(mem + 0);                 // stride 4,390,912 floats
  float* fc_p1 = (float*)(mem + 17563648);

  // 1. LN1: x -> xnorm (bf16)
  ln_kernel<<<B_ * S_, 256, 0, stream>>>(x, n1w, n1b, xnorm);

  // 2. convert rq|rk|qkv|proj weights (all contiguous) into wslot [0:6M)
  conv4_kernel<<<6144, 256, 0, stream>>>(rq_w, 1 << 20, rk_w, 1 << 20,
                                         qkv_w, 3 << 20, proj_w, 1 << 20, wslot);

  // 3. fused rqk + qkv GEMM (1304 blocks, XCD-swizzled)
  fused_rqk_qkv<<<1304, 256, 0, stream>>>(xnorm, wslot, rq_b, rk_b, qkv_b,
                                          qr, kr, qkvb);

  // 4. l2norm qr and kr in one launch
  l2norm2_kernel<<<4096, 256, 0, stream>>>(qr, kr);

  // 5. scores split-K x2 -> partial slices (streaming stores, no atomics)
  mfma_gemm<6><<<dim3(8, 32, 2), 256, 0, stream>>>(qr, 0LL, kr,
      2048, 1024, 1024, 512, 1024, 1LL << 20, 1LL << 20,
      nullptr, nullptr, 10492928, nullptr, nullptr, sc_p0);

  // 6. top-32 routing with fused slice-reduce (+pos, diag)
  topk_kernel<<<512, 256, 0, stream>>>(sc_p0, sc_p1, pos, routes, logw);

  // 7. attention -> attn (bf16)
  attn_cls_p1<<<dim3(NS_, B_ * H_), 256, 0, stream>>>(qkvb, part);
  attn_cls_p2<<<B_ * H_, 64, 0, stream>>>(part, attn);
  attn_patch_kernel<<<B_ * P_ * H_, 64, 0, stream>>>(qkvb, routes, logw, attn);

  // 8. proj split-K x2 -> partial slices
  mfma_gemm<6><<<dim3(8, 33, 2), 256, 0, stream>>>(attn, 0LL, wslot + (5 << 20),
      2050, 1024, 1024, 512, 2050, 0LL, 0LL,
      nullptr, nullptr, 2099200, nullptr, nullptr, pr_p0);

  // 9. convert fc1|fc2 weights into wslot [0:8M) (old weights dead)
  conv4_kernel<<<8192, 256, 0, stream>>>(fc1_w, 1 << 22, fc2_w, 1 << 22,
                                         nullptr, 0, nullptr, 0, wslot);

  // 10. fused residual+LN2: x1 = x + proj_b + p0 + p1; xnorm = LN(x1)
  ln2res_kernel<<<B_ * S_, 256, 0, stream>>>(x, proj_b, pr_p0, pr_p1,
                                             n2w, n2b, x1, xnorm);

  // 11. MLP: fc1 -> hbuf (bf16, gelu); fc2 split-K x2 -> partial slices;
  //     final fused reduce out = x1 + fc2_b + p0 + p1
  mfma_gemm<3><<<dim3(32, 33), 256, 0, stream>>>(xnorm, 0LL, wslot,
      2050, 4096, 1024, 1024, 2050, 0LL, 0LL,
      fc1_b, nullptr, 0, hbuf, nullptr, nullptr);
  mfma_gemm<6><<<dim3(8, 33, 2), 256, 0, stream>>>(hbuf, 0LL, wslot + (1 << 22),
      2050, 1024, 4096, 2048, 2050, 0LL, 0LL,
      nullptr, nullptr, 4390912, nullptr, nullptr, fc_p0);
  fc2red_kernel<<<B_ * S_, 256, 0, stream>>>(x1, fc2_b, fc_p0, fc_p1, out);
}

// Round 17
// 370.121 us; speedup vs baseline: 1.0500x; 1.0173x over previous
//
#include <hip/hip_runtime.h>
#include <hip/hip_bf16.h>
#include <math.h>

typedef unsigned short u16;
typedef __attribute__((ext_vector_type(8))) short short8;
typedef __attribute__((ext_vector_type(4))) float f32x4;

#define B_ 2
#define S_ 1025
#define D_ 1024
#define H_ 16
#define HD_ 64
#define P_ 1024
#define K_ 32
#define NS_ 16   // attn_cls S-splits

static constexpr float TEMP_ = 0.1f;
static constexpr float SCALE_ = 0.125f;
static constexpr float EPS_LN_ = 1e-5f;

__device__ __forceinline__ float bf2f(u16 u) {
  unsigned int t = ((unsigned int)u) << 16;
  float f;
  __builtin_memcpy(&f, &t, 4);
  return f;
}
__device__ __forceinline__ u16 f2bf(float f) {
  __hip_bfloat16 h = __float2bfloat16(f);
  u16 u;
  __builtin_memcpy(&u, &h, 2);
  return u;
}
__device__ __forceinline__ float gelu_f(float x) {
  return 0.5f * x * (1.0f + erff(x * 0.70710678118654752f));
}

typedef __attribute__((address_space(1))) const unsigned int gas_u32;
typedef __attribute__((address_space(3))) unsigned int las_u32;
__device__ __forceinline__ void g2l16(const void* g, void* l) {
  __builtin_amdgcn_global_load_lds((gas_u32*)g, (las_u32*)l, 16, 0, 0);
}

// ---- fused flat f32->bf16 convert of up to 4 contiguous tensors ----
__global__ __launch_bounds__(256) void conv4_kernel(
    const float* __restrict__ s0, int n0, const float* __restrict__ s1, int n1,
    const float* __restrict__ s2, int n2, const float* __restrict__ s3, int n3,
    u16* __restrict__ dst) {
  const int e = (blockIdx.x * 256 + threadIdx.x) * 4;
  const float* src;
  int off;
  if (e < n0) { src = s0; off = e; }
  else if (e < n0 + n1) { src = s1; off = e - n0; }
  else if (e < n0 + n1 + n2) { src = s2; off = e - n0 - n1; }
  else if (e < n0 + n1 + n2 + n3) { src = s3; off = e - n0 - n1 - n2; }
  else return;
  float4 t = *reinterpret_cast<const float4*>(src + off);
  ushort4 o;
  o.x = f2bf(t.x); o.y = f2bf(t.y); o.z = f2bf(t.z); o.w = f2bf(t.w);
  *reinterpret_cast<ushort4*>(dst + e) = o;
}

// ---- block reductions (256 threads) ----
__device__ __forceinline__ float block_sum256(float v, float* red4) {
  for (int off = 32; off > 0; off >>= 1) v += __shfl_down(v, off);
  if ((threadIdx.x & 63) == 0) red4[threadIdx.x >> 6] = v;
  __syncthreads();
  float r = red4[0] + red4[1] + red4[2] + red4[3];
  __syncthreads();
  return r;
}
__device__ __forceinline__ float block_max256(float v, float* red4) {
  for (int off = 32; off > 0; off >>= 1) v = fmaxf(v, __shfl_down(v, off));
  if ((threadIdx.x & 63) == 0) red4[threadIdx.x >> 6] = v;
  __syncthreads();
  float r = fmaxf(fmaxf(red4[0], red4[1]), fmaxf(red4[2], red4[3]));
  __syncthreads();
  return r;
}

// ---- LayerNorm f32 in -> bf16 out ----
__global__ __launch_bounds__(256) void ln_kernel(const float* __restrict__ x,
                                                 const float* __restrict__ w,
                                                 const float* __restrict__ b,
                                                 u16* __restrict__ out) {
  __shared__ float red4[4];
  const long long base = (long long)blockIdx.x * D_;
  float v[4];
  float s = 0.f, ss = 0.f;
#pragma unroll
  for (int u = 0; u < 4; ++u) {
    int d = threadIdx.x + u * 256;
    float f = x[base + d];
    v[u] = f; s += f; ss += f * f;
  }
  float tot = block_sum256(s, red4);
  float tot2 = block_sum256(ss, red4);
  float mean = tot * (1.0f / D_);
  float var = tot2 * (1.0f / D_) - mean * mean;
  float rstd = rsqrtf(var + EPS_LN_);
#pragma unroll
  for (int u = 0; u < 4; ++u) {
    int d = threadIdx.x + u * 256;
    out[base + d] = f2bf((v[u] - mean) * rstd * w[d] + b[d]);
  }
}

// ---- fused residual + LN2: x1 = x + proj_b + p0 + p1; xnorm = LN(x1) ----
__global__ __launch_bounds__(256) void ln2res_kernel(
    const float* __restrict__ x, const float* __restrict__ pb,
    const float* __restrict__ p0, const float* __restrict__ p1,
    const float* __restrict__ w, const float* __restrict__ b,
    float* __restrict__ x1, u16* __restrict__ out) {
  __shared__ float red4[4];
  const long long base = (long long)blockIdx.x * D_;
  float v[4];
  float s = 0.f, ss = 0.f;
#pragma unroll
  for (int u = 0; u < 4; ++u) {
    int d = threadIdx.x + u * 256;
    float f = x[base + d] + pb[d] + p0[base + d] + p1[base + d];
    x1[base + d] = f;
    v[u] = f; s += f; ss += f * f;
  }
  float tot = block_sum256(s, red4);
  float tot2 = block_sum256(ss, red4);
  float mean = tot * (1.0f / D_);
  float var = tot2 * (1.0f / D_) - mean * mean;
  float rstd = rsqrtf(var + EPS_LN_);
#pragma unroll
  for (int u = 0; u < 4; ++u) {
    int d = threadIdx.x + u * 256;
    out[base + d] = f2bf((v[u] - mean) * rstd * w[d] + b[d]);
  }
}

// ---- final fused reduce: out = x1 + fc2_b + p0 + p1 ----
__global__ __launch_bounds__(256) void fc2red_kernel(
    const float* __restrict__ x1, const float* __restrict__ b,
    const float* __restrict__ p0, const float* __restrict__ p1,
    float* __restrict__ out) {
  const long long base = (long long)blockIdx.x * D_;
#pragma unroll
  for (int u = 0; u < 4; ++u) {
    int d = threadIdx.x + u * 256;
    out[base + d] = x1[base + d] + b[d] + p0[base + d] + p1[base + d];
  }
}

// ---- L2 normalize qr then kr rows in one launch (4096 blocks) ----
__global__ __launch_bounds__(256) void l2norm2_kernel(u16* __restrict__ qr,
                                                      u16* __restrict__ kr) {
  __shared__ float red4[4];
  const int row = blockIdx.x;
  u16* x = (row < 2048) ? qr + (long long)row * D_
                        : kr + (long long)(row - 2048) * D_;
  float v[4];
  float ss = 0.f;
#pragma unroll
  for (int u = 0; u < 4; ++u) {
    int d = threadIdx.x + u * 256;
    v[u] = bf2f(x[d]);
    ss += v[u] * v[u];
  }
  float tot = block_sum256(ss, red4);
  float inv = 1.0f / fmaxf(sqrtf(tot), 1e-12f);
#pragma unroll
  for (int u = 0; u < 4; ++u) {
    int d = threadIdx.x + u * 256;
    x[d] = f2bf(v[u] * inv);
  }
}

// ---- MFMA GEMM body: out[n,m] = sum_k A[n,k]*W[m,k], 64x128 tile, BK=64 ----
// r13/r16-measured single-buffer form (376.5 us best). Ledger:
//  r3  counted-vmcnt dbuf      REGRESSED (+34 us)
//  r7  deeper split-K          REGRESSED (+39 us, atomic RMW tax)
//  r8  XCD swizzle             KEPT (FETCH -76%)
//  r10 64x128 tile             NULL (kept: less LDS)
//  r13 atomic-free split-K     WIN  (-20.5 us)
//  r15 1-barrier prefetch dbuf REGRESSED (+5 us; barrier drains vmcnt anyway)
//  => source-level pipelining of this 2-barrier structure is CLOSED.
// Staging: A 2 chunks + W 4 chunks of (32 rows x 64 k); k granules (16B)
// XOR-swizzled by (row&7) on the GLOBAL src addr -> ds_read conflict-free.
// MODE 0: RQK : m<1024 -> outU=bf16(v+bias[m]); else outU2=bf16(v+bias2[m-1024])
// MODE 2: BIAS: outU = bf16(v + bias[bias_off+m])
// MODE 3: GELU: outU = bf16(gelu(v + bias[bias_off+m]))
// MODE 6: PART: outF[bz*bias_off + n*M + m] = v  (bias_off = slice stride, floats)
template <int MODE>
__device__ __forceinline__ void gemm_body(
    u16* sA, u16* sW,
    const u16* __restrict__ A, long long a_off, const u16* __restrict__ W,
    int N, int M, int Kd, int klen, int rpb, long long a_bs, long long w_bs,
    const float* __restrict__ bias, const float* __restrict__ bias2, int bias_off,
    u16* __restrict__ outU, u16* __restrict__ outU2, float* __restrict__ outF,
    int bx, int by, int bz) {
  const int tid = threadIdx.x;
  const int lane = tid & 63;
  const int q4 = lane >> 4;
  const int r16 = lane & 15;
  const int wave = tid >> 6;
  const int wr = (wave & 1) * 32;   // wave row-group: 2 x 32 rows
  const int wc = (wave >> 1) * 64;  // wave col-group: 2 x 64 cols
  const int row0 = by * 64;
  const int col0 = bx * 128;
  const int batch = row0 / rpb;
  const u16* Ab = A + a_off + (long long)batch * a_bs +
                  (long long)(row0 - batch * rpb) * Kd;
  const u16* Wb = W + (long long)batch * w_bs + (long long)col0 * Kd;
  const int rmax = N - 1 - row0;
  // staging: chunks of (32 rows x 64 k); lds dest = c*2048 + tid*8 (u16)
  const int srow = tid >> 3;                     // row within chunk (0..31)
  const int kx = ((tid & 7) ^ (srow & 7)) * 8;   // swizzled global k-granule
  const int kbeg = bz * klen;
  const int niter = klen >> 6;
  f32x4 acc[2][4] = {};
  for (int it = 0; it < niter; ++it) {
    const int k0 = kbeg + it * 64;
#pragma unroll
    for (int c = 0; c < 2; ++c) {
      const int rg = c * 32 + srow;
      g2l16(Ab + (long long)min(rg, rmax) * Kd + kx + k0, &sA[c * 2048 + tid * 8]);
    }
#pragma unroll
    for (int c = 0; c < 4; ++c) {
      const int rg = c * 32 + srow;
      g2l16(Wb + (long long)rg * Kd + kx + k0, &sW[c * 2048 + tid * 8]);
    }
    __builtin_amdgcn_s_waitcnt(0);
    __syncthreads();
#pragma unroll
    for (int s = 0; s < 2; ++s) {
      short8 a[2], b[4];
      const int ks = ((s * 4 + q4) ^ (r16 & 7)) * 8;
#pragma unroll
      for (int i = 0; i < 2; ++i)
        a[i] = *reinterpret_cast<const short8*>(&sA[(wr + i * 16 + r16) * 64 + ks]);
#pragma unroll
      for (int j = 0; j < 4; ++j)
        b[j] = *reinterpret_cast<const short8*>(&sW[(wc + j * 16 + r16) * 64 + ks]);
#pragma unroll
      for (int i = 0; i < 2; ++i)
#pragma unroll
        for (int j = 0; j < 4; ++j)
          acc[i][j] = __builtin_amdgcn_mfma_f32_16x16x32_bf16(a[i], b[j],
                                                              acc[i][j], 0, 0, 0);
    }
    __syncthreads();
  }
  const long long sbase = (MODE == 6) ? (long long)bz * bias_off : 0;
#pragma unroll
  for (int i = 0; i < 2; ++i) {
#pragma unroll
    for (int reg = 0; reg < 4; ++reg) {
      const int n = row0 + wr + i * 16 + q4 * 4 + reg;
      if (n >= N) continue;
      const long long nrow = (long long)n * M;
#pragma unroll
      for (int j = 0; j < 4; ++j) {
        const int m = col0 + wc + j * 16 + r16;
        float v = acc[i][j][reg];
        if (MODE == 0) {
          if (m < 1024) outU[(long long)n * 1024 + m] = f2bf(v + bias[m]);
          else outU2[(long long)n * 1024 + m - 1024] = f2bf(v + bias2[m - 1024]);
        } else if (MODE == 2) {
          outU[nrow + m] = f2bf(v + bias[bias_off + m]);
        } else if (MODE == 3) {
          outU[nrow + m] = f2bf(gelu_f(v + bias[bias_off + m]));
        } else {  // MODE 6: partial slice streaming store
          outF[sbase + nrow + m] = v;
        }
      }
    }
  }
}

// XCD-aware bijective swizzle (m157/m204): hardware assigns workgroup i to
// XCD (i % 8); remap so each XCD owns a CONTIGUOUS logical chunk. Requires
// nwg % 8 == 0 (all GEMM grids here: 512/528/1056/1304).
__device__ __forceinline__ int xcd_swz(int orig, int nwg) {
  return (orig & 7) * (nwg >> 3) + (orig >> 3);
}

template <int MODE>
__global__ __launch_bounds__(256, 6) void mfma_gemm(
    const u16* __restrict__ A, long long a_off, const u16* __restrict__ W,
    int N, int M, int Kd, int klen, int rpb, long long a_bs, long long w_bs,
    const float* __restrict__ bias, const float* __restrict__ bias2, int bias_off,
    u16* __restrict__ outU, u16* __restrict__ outU2, float* __restrict__ outF) {
  __shared__ u16 sA[64 * 64];
  __shared__ u16 sW[128 * 64];
  const int gx = gridDim.x, gy = gridDim.y;
  const int nwg = gx * gy * gridDim.z;
  const int orig = blockIdx.x + gx * (blockIdx.y + gy * blockIdx.z);
  const int swz = xcd_swz(orig, nwg);
  const int bx = swz % gx;
  const int t = swz / gx;
  const int by = t % gy;
  const int bz = t / gy;
  gemm_body<MODE>(sA, sW, A, a_off, W, N, M, Kd, klen, rpb, a_bs, w_bs,
                  bias, bias2, bias_off, outU, outU2, outF, bx, by, bz);
}

// ---- fused rqk + qkv GEMM: logical ids [0,512) do rq|rk, [512,1304) do qkv ----
__global__ __launch_bounds__(256, 6) void fused_rqk_qkv(
    const u16* __restrict__ xnorm, const u16* __restrict__ wslot,
    const float* __restrict__ rq_b, const float* __restrict__ rk_b,
    const float* __restrict__ qkv_b,
    u16* __restrict__ qr, u16* __restrict__ kr, u16* __restrict__ qkvb) {
  __shared__ u16 sA[64 * 64];
  __shared__ u16 sW[128 * 64];
  const int id = xcd_swz(blockIdx.x, 1304);  // 1304 % 8 == 0, bijective
  if (id < 512) {
    gemm_body<0>(sA, sW, xnorm, 1024LL, wslot,
                 2048, 2048, 1024, 1024, 1024, (long long)S_ * D_, 0LL,
                 rq_b, rk_b, 0, qr, kr, nullptr, id & 15, id >> 4, 0);
  } else {
    const int id2 = id - 512;
    gemm_body<2>(sA, sW, xnorm, 0LL, wslot + (2 << 20),
                 2050, 3072, 1024, 1024, 2050, 0LL, 0LL,
                 qkv_b, nullptr, 0, qkvb, nullptr, nullptr, id2 % 24, id2 / 24, 0);
  }
}

// ---- top-32 with fused slice-reduce: v = s0 + s1 + pos, diag -1e9 ----
__global__ __launch_bounds__(256) void topk_kernel(const float* __restrict__ s0,
                                                   const float* __restrict__ s1,
                                                   const float* __restrict__ pos,
                                                   int* __restrict__ routes,
                                                   float* __restrict__ logw) {
  const int row = blockIdx.x * 4 + (threadIdx.x >> 6);
  const int lane = threadIdx.x & 63;
  const int p = row & (P_ - 1);
  const float* r0 = s0 + (long long)row * P_;
  const float* r1 = s1 + (long long)row * P_;
  const float* pr = pos + (long long)p * P_;
  float v[16];
#pragma unroll
  for (int j = 0; j < 16; ++j) {
    const int q = j * 64 + lane;
    float t = r0[q] + r1[q] + pr[q];
    v[j] = (q == p) ? -1e9f : t;
  }
  float selv = 0.f;
  int seli = 0;
  for (int t = 0; t < K_; ++t) {
    float bv = v[0];
    int bj = 0;
#pragma unroll
    for (int j = 1; j < 16; ++j)
      if (v[j] > bv) { bv = v[j]; bj = j; }
    int bi = bj * 64 + lane;
#pragma unroll
    for (int off = 1; off < 64; off <<= 1) {
      float ov = __shfl_xor(bv, off);
      int oi = __shfl_xor(bi, off);
      if (ov > bv || (ov == bv && oi < bi)) { bv = ov; bi = oi; }
    }
    if (lane == t) { selv = bv; seli = bi; }
    if ((bi & 63) == lane) v[bi >> 6] = -3.0e38f;
  }
  const float sc = selv * (1.0f / TEMP_);
  const float mt = __shfl(sc, 0);
  float e = (lane < K_) ? expf(sc - mt) : 0.f;
  float sum = e;
#pragma unroll
  for (int off = 1; off < 64; off <<= 1) sum += __shfl_xor(sum, off);
  if (lane < K_) {
    const float lw = sc - mt - logf(sum);
    logw[(long long)row * K_ + lane] = fmaxf(lw, -10.0f);
    routes[(long long)row * K_ + lane] = seli;
  }
}

// ---- cls attention phase 1: grid (NS_, B*H); chunked online stats ----
__global__ __launch_bounds__(256) void attn_cls_p1(const u16* __restrict__ qkv,
                                                   float* __restrict__ part) {
  __shared__ float qs[HD_];
  __shared__ float lg[65];
  __shared__ float red4[4];
  __shared__ float sacc[4][HD_];
  const int ck = blockIdx.x;
  const int bh = blockIdx.y;
  const int b = bh >> 4, h = bh & 15;
  const int tid = threadIdx.x;
  const int lane = tid & 63;
  const int wv = tid >> 6;
  const int s0 = ck * 65;
  const int rows = min(65, S_ - s0);
  const long long base = (long long)b * S_ * 3072;
  if (tid < HD_) qs[tid] = bf2f(qkv[base + h * HD_ + tid]);
  __syncthreads();
  float lmax = -3.0e38f;
  if (tid < rows) {
    const u16* kp = qkv + base + (long long)(s0 + tid) * 3072 + 1024 + h * HD_;
    float d = 0.f;
#pragma unroll
    for (int c = 0; c < 8; ++c) {
      short8 kv = *reinterpret_cast<const short8*>(kp + c * 8);
#pragma unroll
      for (int e = 0; e < 8; ++e) d += qs[c * 8 + e] * bf2f((u16)kv[e]);
    }
    d *= SCALE_;
    lg[tid] = d;
    lmax = d;
  }
  const float m = block_max256(lmax, red4);
  float e = 0.f;
  if (tid < rows) {
    e = expf(lg[tid] - m);
    lg[tid] = e;
  }
  const float l = block_sum256(e, red4);
  __syncthreads();
  float acc = 0.f;
  for (int r = wv; r < rows; r += 4)
    acc += lg[r] * bf2f(qkv[base + (long long)(s0 + r) * 3072 + 2048 + h * HD_ + lane]);
  sacc[wv][lane] = acc;
  __syncthreads();
  float* pc = part + ((long long)bh * NS_ + ck) * 66;
  if (tid < HD_)
    pc[tid] = sacc[0][tid] + sacc[1][tid] + sacc[2][tid] + sacc[3][tid];
  if (tid == 64) pc[64] = m;
  if (tid == 65) pc[65] = l;
}

// ---- cls attention phase 2: combine; one block (64 thr) per (b,h) ----
__global__ __launch_bounds__(64) void attn_cls_p2(const float* __restrict__ part,
                                                  u16* __restrict__ out) {
  const int bh = blockIdx.x;
  const int b = bh >> 4, h = bh & 15;
  const int tid = threadIdx.x;
  const float* pb = part + (long long)bh * NS_ * 66;
  float M = -3.0e38f;
#pragma unroll
  for (int c = 0; c < NS_; ++c) M = fmaxf(M, pb[c * 66 + 64]);
  float L = 0.f, a = 0.f;
#pragma unroll
  for (int c = 0; c < NS_; ++c) {
    const float w = expf(pb[c * 66 + 64] - M);
    L += pb[c * 66 + 65] * w;
    a += pb[c * 66 + tid] * w;
  }
  out[(long long)b * S_ * D_ + h * HD_ + tid] = f2bf(a / L);
}

// ---- routed patch attention: one wave per (b, p, head-PAIR) ----
// r16 profile: 43.7 us, MfmaUtil 0, VALUBusy 46%, HBM 3.6% -- VALU/L2-gather
// bound with HALF the wave idle in the QK phase (if tid<32) and scalar 2B
// bf16 V loads. Fix: 2 heads per wave (they share routes): QK uses all 64
// lanes (lane = route k + 32*hh); softmax per 32-lane half (shfl_xor off<32
// never crosses bit 5); PV loads ushort2 (4B) covering the pair's 128
// contiguous dims. Grid halves to B*P*8 = 16384.
__global__ __launch_bounds__(64) void attn_patch_kernel(const u16* __restrict__ qkv,
                                                        const int* __restrict__ routes,
                                                        const float* __restrict__ logw,
                                                        u16* __restrict__ out) {
  __shared__ float qs[128];     // head-pair Q
  __shared__ float wk[2][K_];
  __shared__ int sidx[K_];
  const int bid = blockIdx.x;
  const int hp = bid & 7;               // head-pair index 0..7
  const int p = (bid >> 3) & (P_ - 1);
  const int b = bid >> 13;
  const int tid = threadIdx.x;          // 0..63
  const int h0 = hp * 2;
  const long long base = (long long)b * S_ * 3072;
  const long long ro_base = ((long long)(b * P_ + p)) * K_;
  // Q for both heads: 128 dims, ushort2 per lane (4B aligned)
  {
    const u16* qp = qkv + base + (long long)(1 + p) * 3072 + h0 * HD_;
    ushort2 q2 = *reinterpret_cast<const ushort2*>(qp + 2 * tid);
    qs[2 * tid] = bf2f(q2.x);
    qs[2 * tid + 1] = bf2f(q2.y);
  }
  if (tid < K_) sidx[tid] = routes[ro_base + tid];
  __syncthreads();
  // QK: all 64 lanes -- lane = (route k, head h0+hh)
  const int k = tid & 31;
  const int hh = tid >> 5;
  const int r = sidx[k];
  {
    const u16* kp = qkv + base + (long long)(1 + r) * 3072 + 1024 + (h0 + hh) * HD_;
    float d = 0.f;
#pragma unroll
    for (int c = 0; c < 8; ++c) {
      short8 kv = *reinterpret_cast<const short8*>(kp + c * 8);
#pragma unroll
      for (int e = 0; e < 8; ++e) d += qs[hh * 64 + c * 8 + e] * bf2f((u16)kv[e]);
    }
    float lg = d * SCALE_ + logw[ro_base + k];
    // softmax within each 32-lane half
    float m = lg;
#pragma unroll
    for (int off = 1; off < 32; off <<= 1) m = fmaxf(m, __shfl_xor(m, off));
    float e = expf(lg - m);
    float sum = e;
#pragma unroll
    for (int off = 1; off < 32; off <<= 1) sum += __shfl_xor(sum, off);
    wk[hh][k] = e / sum;
  }
  __syncthreads();
  // PV: lane covers dims {2*tid, 2*tid+1} of the pair's 128 contiguous dims;
  // lanes 0-31 -> head h0 (wk[0]), lanes 32-63 -> head h0+1 (wk[1])
  const int hv = tid >> 5;
  float acc0 = 0.f, acc1 = 0.f;
#pragma unroll 4
  for (int kk = 0; kk < K_; ++kk) {
    const float w = wk[hv][kk];
    const u16* vp = qkv + base + (long long)(1 + sidx[kk]) * 3072 + 2048 + h0 * HD_;
    ushort2 v2 = *reinterpret_cast<const ushort2*>(vp + 2 * tid);
    acc0 += w * bf2f(v2.x);
    acc1 += w * bf2f(v2.y);
  }
  u16* op = out + ((long long)b * S_ + 1 + p) * D_ + h0 * HD_;
  ushort2 o2;
  o2.x = f2bf(acc0);
  o2.y = f2bf(acc1);
  *reinterpret_cast<ushort2*>(op + 2 * tid) = o2;
}

extern "C" void kernel_launch(void* const* d_in, const int* in_sizes, int n_in,
                              void* d_out, int out_size, void* d_ws, size_t ws_size,
                              hipStream_t stream) {
  const float* x      = (const float*)d_in[0];
  const float* n1w    = (const float*)d_in[1];
  const float* n1b    = (const float*)d_in[2];
  const float* rq_w   = (const float*)d_in[3];
  const float* rq_b   = (const float*)d_in[4];
  const float* rk_w   = (const float*)d_in[5];
  const float* rk_b   = (const float*)d_in[6];
  const float* pos    = (const float*)d_in[7];
  const float* qkv_w  = (const float*)d_in[8];
  const float* qkv_b  = (const float*)d_in[9];
  const float* proj_w = (const float*)d_in[10];
  const float* proj_b = (const float*)d_in[11];
  const float* n2w    = (const float*)d_in[12];
  const float* n2b    = (const float*)d_in[13];
  const float* fc1_w  = (const float*)d_in[14];
  const float* fc1_b  = (const float*)d_in[15];
  const float* fc2_w  = (const float*)d_in[16];
  const float* fc2_b  = (const float*)d_in[17];
  float* out = (float*)d_out;

  // ---- workspace layout (bytes; ~51.2 MB; evidence: ws >= 59.3 MB) ----
  // Base slots (phase 1):
  char* mem = (char*)d_ws;
  int*   routes = (int*)mem;                        //   262,144
  float* logw   = (float*)(mem + 262144);           //   262,144
  float* part   = (float*)(mem + 524288);           //   262,144
  u16*   wslot  = (u16*)(mem + 786432);             // 16,777,216 (8M elems)
  u16*   xnorm  = (u16*)(mem + 17563648);           //  4,198,400
  u16*   qr     = (u16*)(mem + 21762048);           //  4,198,400 (qr, later attn)
  u16*   attn   = qr;
  u16*   qkvb   = (u16*)(mem + 25960448);           // 12,595,200
  u16*   kr     = (u16*)(mem + 38555648);           //  4,202,496
  u16*   hbuf   = qkvb;                             // spans qkvb+kr (16.8 MB), live fc1->fc2
  float* x1     = (float*)(mem + 42758144);         //  8,396,800
  // Split-K partial-slice overlays (each target dead at write time; verified
  // dispatch-by-dispatch in r10/r11 aliasing audit):
  //  scores: p0 over dead rq/rk/qkv weights; p1 over scores/x1 slot (pre-x1)
  float* sc_p0 = (float*)(mem + 786432);            // stride 10,492,928 floats
  float* sc_p1 = (float*)(mem + 42758144);
  //  proj:   p0/p1 over dead qkvb+kr (after attn); consumed by ln2res
  float* pr_p0 = (float*)(mem + 25960448);          // stride 2,099,200 floats
  float* pr_p1 = (float*)(mem + 34357248);
  //  fc2:    p0 over dead routes/logw/part + fc1 weights (after fc1);
  //          p1 over dead xnorm+attn; consumed by fc2red
  float* fc_p0 = (float*)(mem + 0);                 // stride 4,390,912 floats
  float* fc_p1 = (float*)(mem + 17563648);

  // 1. LN1: x -> xnorm (bf16)
  ln_kernel<<<B_ * S_, 256, 0, stream>>>(x, n1w, n1b, xnorm);

  // 2. convert rq|rk|qkv|proj weights (all contiguous) into wslot [0:6M)
  conv4_kernel<<<6144, 256, 0, stream>>>(rq_w, 1 << 20, rk_w, 1 << 20,
                                         qkv_w, 3 << 20, proj_w, 1 << 20, wslot);

  // 3. fused rqk + qkv GEMM (1304 blocks, XCD-swizzled)
  fused_rqk_qkv<<<1304, 256, 0, stream>>>(xnorm, wslot, rq_b, rk_b, qkv_b,
                                          qr, kr, qkvb);

  // 4. l2norm qr and kr in one launch
  l2norm2_kernel<<<4096, 256, 0, stream>>>(qr, kr);

  // 5. scores split-K x2 -> partial slices (streaming stores, no atomics)
  mfma_gemm<6><<<dim3(8, 32, 2), 256, 0, stream>>>(qr, 0LL, kr,
      2048, 1024, 1024, 512, 1024, 1LL << 20, 1LL << 20,
      nullptr, nullptr, 10492928, nullptr, nullptr, sc_p0);

  // 6. top-32 routing with fused slice-reduce (+pos, diag)
  topk_kernel<<<512, 256, 0, stream>>>(sc_p0, sc_p1, pos, routes, logw);

  // 7. attention -> attn (bf16); patch kernel = one wave per (b,p,head-pair)
  attn_cls_p1<<<dim3(NS_, B_ * H_), 256, 0, stream>>>(qkvb, part);
  attn_cls_p2<<<B_ * H_, 64, 0, stream>>>(part, attn);
  attn_patch_kernel<<<B_ * P_ * (H_ / 2), 64, 0, stream>>>(qkvb, routes, logw, attn);

  // 8. proj split-K x2 -> partial slices
  mfma_gemm<6><<<dim3(8, 33, 2), 256, 0, stream>>>(attn, 0LL, wslot + (5 << 20),
      2050, 1024, 1024, 512, 2050, 0LL, 0LL,
      nullptr, nullptr, 2099200, nullptr, nullptr, pr_p0);

  // 9. convert fc1|fc2 weights into wslot [0:8M) (old weights dead)
  conv4_kernel<<<8192, 256, 0, stream>>>(fc1_w, 1 << 22, fc2_w, 1 << 22,
                                         nullptr, 0, nullptr, 0, wslot);

  // 10. fused residual+LN2: x1 = x + proj_b + p0 + p1; xnorm = LN(x1)
  ln2res_kernel<<<B_ * S_, 256, 0, stream>>>(x, proj_b, pr_p0, pr_p1,
                                             n2w, n2b, x1, xnorm);

  // 11. MLP: fc1 -> hbuf (bf16, gelu); fc2 split-K x2 -> partial slices;
  //     final fused reduce out = x1 + fc2_b + p0 + p1
  mfma_gemm<3><<<dim3(32, 33), 256, 0, stream>>>(xnorm, 0LL, wslot,
      2050, 4096, 1024, 1024, 2050, 0LL, 0LL,
      fc1_b, nullptr, 0, hbuf, nullptr, nullptr);
  mfma_gemm<6><<<dim3(8, 33, 2), 256, 0, stream>>>(hbuf, 0LL, wslot + (1 << 22),
      2050, 1024, 4096, 2048, 2050, 0LL, 0LL,
      nullptr, nullptr, 4390912, nullptr, nullptr, fc_p0);
  fc2red_kernel<<<B_ * S_, 256, 0, stream>>>(x1, fc2_b, fc_p0, fc_p1, out);
}